// Round 3
// baseline (427.306 us; speedup 1.0000x reference)
//
#include <hip/hip_runtime.h>
#include <stdint.h>

// Depth-to-space (r=4, x-major channel order), float32 in AND out.
// in:  (16, 4096, 32, 32) fp32   out: (16, 256, 128, 128) fp32
// out[b,c,y,x] = in[b, c*16 + 4*(x%4) + (y%4), y/4, x/4]
//
// Thread -> 4 contiguous output floats (one float4 store) at x in [4k,4k+4),
// sourced from 4 input channels (xr=0..3) at column xb=k: four scalar dword
// loads. Lanes k=0..31 of a row jointly read one full 128-B input row per
// load instruction (contiguous, fully consumed) and write one 512-B output
// row per store instruction (fully contiguous).

__global__ __launch_bounds__(256) void ScaleTransfer_kernel(
    const float* __restrict__ in, float* __restrict__ out)
{
    // gridDim.x = 16*256*16 = 65536; block = 256 = (8 rows x 32 cols)
    const int blk  = blockIdx.x;
    const int yblk = blk & 15;       // 16 blocks of 8 rows -> Y=128
    const int bc   = blk >> 4;       // b*256 + c

    const int t         = threadIdx.x;
    const int row_local = t >> 5;    // 0..7
    const int k         = t & 31;    // x chunk: x in [4k, 4k+4)

    const int y  = yblk * 8 + row_local;   // 0..127
    const int yb = y >> 2;
    const int yr = y & 3;

    const int b = bc >> 8;
    const int c = bc & 255;

    // input flat: ((b*4096 + ch)*32 + yb)*32 + xb, ch = c*16 + 4*xr + yr
    const size_t src_off =
        (((size_t)b * 4096 + (size_t)c * 16 + yr) * 32 + yb) * 32 + k;
    const float* src = in + src_off;

    // xr steps channel by 4 -> 4*1024 = 4096 floats
    float4 o;
    o.x = src[0 * 4096];   // xr=0
    o.y = src[1 * 4096];   // xr=1
    o.z = src[2 * 4096];   // xr=2
    o.w = src[3 * 4096];   // xr=3

    const size_t dst_off = (((size_t)bc * 128) + y) * 128 + 4 * k;
    *(float4*)(out + dst_off) = o;
}

extern "C" void kernel_launch(void* const* d_in, const int* in_sizes, int n_in,
                              void* d_out, int out_size, void* d_ws, size_t ws_size,
                              hipStream_t stream) {
    const float* in = (const float*)d_in[0];
    float* out = (float*)d_out;
    // 16 batches * 256 out-channels * 16 row-blocks
    dim3 grid(16 * 256 * 16);
    dim3 block(256);
    ScaleTransfer_kernel<<<grid, block, 0, stream>>>(in, out);
}